// Round 8
// baseline (214.586 us; speedup 1.0000x reference)
//
#include <hip/hip_runtime.h>

// LabelGenerator: masks [32,1,768,768] f32 in {0,1}
//  out0 = 35x35 box mean (SAME, zero pad)      -> f32 [32,768,768]
//  out1 = pfm: mask?1 : (31x31 dilation?0 : 2) -> f32 values 0/1/2
// R8: rolling pipelined kernel. Prologue stages 34 halo rows; then 4 chunks
// of 12 rows: A (ballot-pack bits) -> H (h35|mask<<6|or31<<7 packed bytes
// into 48-row LDS ring) -> B (per-column scalar sliding sums + stores).
// Global loads of chunk j+1 overlap store drain of chunk j -> HBM never idle.
// Dilation on a 0/1 mask == (31x31 box sum >= 1).

#define BATCH 32
#define HH 768
#define WW 768
#define NPIX (HH * WW)

constexpr int TYO  = 48;               // output rows per block
constexpr int NSEG = 12;               // 768/64 u64 segments per row
constexpr int SSEG = NSEG + 2;         // +2 zero-pad segments
constexpr int NT   = 768;              // threads per block (12 waves)
constexpr int CT   = 192;              // 4-col groups per row (H phase)
constexpr int PRO  = 34;               // prologue rows (halo + init window - 1)
constexpr int RING = 48;               // hm ring rows (span needed: 47)

__device__ __forceinline__ int m48(int x) { return (x >= RING) ? x - RING : x; }

__global__ __launch_bounds__(NT)
void label_gen_roll(const float* __restrict__ in, float* __restrict__ out) {
    __shared__ unsigned long long sbits[PRO][SSEG];   // 3808 B (chunks use 0..11)
    __shared__ unsigned int hm[RING][CT];             // 36864 B packed bytes

    const int tid  = threadIdx.x;
    const int lane = tid & 63;
    const int wv   = tid >> 6;          // 0..11
    const int y0   = blockIdx.x * TYO;
    const int b    = blockIdx.y;
    const float* __restrict__ src = in + (size_t)b * NPIX;

    // ---- A: ballot-pack image row (y0-17+lr) into sbits[slot] ----
    auto packrow = [&](int lr, int slot) {
        const int r = y0 - 17 + lr;
        unsigned long long bb[NSEG];
        if ((unsigned)r < (unsigned)HH) {          // wave-uniform branch
            const float* rp = src + (size_t)r * WW;
            #pragma unroll
            for (int j = 0; j < NSEG; ++j)
                bb[j] = __ballot(rp[64 * j + lane] > 0.5f);
        } else {
            #pragma unroll
            for (int j = 0; j < NSEG; ++j) bb[j] = 0ull;
        }
        if (lane == 0) {
            sbits[slot][0] = 0ull;
            #pragma unroll
            for (int j = 0; j < NSEG; ++j) sbits[slot][j + 1] = bb[j];
            sbits[slot][SSEG - 1] = 0ull;
        }
    };

    // ---- H: horizontal values for 4 cols of one bit-row -> hm ring ----
    const int gH  = tid / CT;           // 0..3
    const int ctH = tid - gH * CT;      // 0..191
    const int sH  = 4 * ctH - 17;
    const int qH  = (sH >> 6) + 1;      // padded u64 index (arith shift)
    const int shH = sH & 63;            // odd -> never 0
    const unsigned long long M35 = (1ull << 35) - 1;
    auto bit = [](unsigned long long w, int k) -> unsigned {
        return (unsigned)((w >> k) & 1ull);
    };
    auto hrow = [&](int slot, int ring) {
        const unsigned long long w =
            (sbits[slot][qH] >> shH) | (sbits[slot][qH + 1] << (64 - shH));
        const unsigned h0 = (unsigned)__popcll(w & M35);
        const unsigned h1 = h0 + bit(w, 35) - bit(w, 0);
        const unsigned h2 = h1 + bit(w, 36) - bit(w, 1);
        const unsigned h3 = h2 + bit(w, 37) - bit(w, 2);
        unsigned long long sm = w | (w >> 1);          // 16-smear
        sm |= sm >> 2; sm |= sm >> 4; sm |= sm >> 8;
        const unsigned o4 = (unsigned)(((sm >> 2) | (sm >> 17)) & 0xFull);
        const unsigned m4 = (unsigned)((w >> 17) & 0xFull);
        hm[ring][ctH] = h0 | (h1 << 8) | (h2 << 16) | (h3 << 24)
                      | ((m4 & 1u) << 6)  | ((m4 & 2u) << 13)
                      | ((m4 & 4u) << 20) | ((m4 & 8u) << 27)
                      | ((o4 & 1u) << 7)  | ((o4 & 2u) << 14)
                      | ((o4 & 4u) << 21) | ((o4 & 8u) << 28);
    };

    // ---- prologue: rows 0..33 ----
    for (int lr = wv; lr < PRO; lr += 12) packrow(lr, lr);
    __syncthreads();
    for (int lr = gH; lr < PRO; lr += 4) hrow(lr, lr);
    __syncthreads();

    // ---- B state: one thread per column ----
    const int wrd = tid >> 2;           // hm word index (4-lane broadcast)
    const int sh8 = (tid & 3) * 8;
    int v35 = 0, c31 = 0;
    #pragma unroll
    for (int k = 0; k < PRO; ++k) {
        const unsigned x = hm[k][wrd] >> sh8;
        v35 += (int)(x & 0x3Fu);
        if (k >= 2 && k <= 32) c31 += (int)((x >> 7) & 1u);
    }

    float* orow = out + (size_t)b * NPIX + (size_t)y0 * WW + tid;
    float* prow = orow + (size_t)BATCH * NPIX;

    // ---- main loop: 4 chunks x 12 rows ----
    for (int j = 0; j < 4; ++j) {
        const int base = PRO + 12 * j;               // first new row this chunk
        packrow(base + wv, wv);                      // 12 waves, 1 row each
        __syncthreads();                             // A done; also fences B(j-1) vs hrow(j)
        for (int r = gH; r < 12; r += 4) hrow(r, m48(base + r));
        __syncthreads();
        for (int ii = 0; ii < 12; ++ii) {
            const int i = 12 * j + ii;               // output row index 0..47
            // slide v35: add row i+34, sub row i-1 (none at i=0)
            const unsigned xe = hm[m48(i + 34)][wrd] >> sh8;
            v35 += (int)(xe & 0x3Fu);
            if (i > 0) {
                const unsigned xl = hm[m48(i - 1)][wrd] >> sh8;
                const unsigned xa = hm[m48(i + 32)][wrd] >> sh8;
                const unsigned xs = hm[m48(i + 1)][wrd] >> sh8;
                v35 -= (int)(xl & 0x3Fu);
                c31 += (int)((xa >> 7) & 1u) - (int)((xs >> 7) & 1u);
            }
            const unsigned xc = hm[m48(i + 17)][wrd] >> sh8;   // center (mask)
            *orow = (float)v35 * (1.0f / 1225.0f);
            *prow = ((xc >> 6) & 1u) ? 1.0f : (c31 ? 0.0f : 2.0f);
            orow += WW; prow += WW;
        }
        // no barrier: next packrow touches only sbits (already consumed by hrow,
        // fenced by the post-A barrier); B reads hm rows <= base+11, hrow(j+1)
        // writes are fenced by the next post-A barrier.
    }
}

extern "C" void kernel_launch(void* const* d_in, const int* in_sizes, int n_in,
                              void* d_out, int out_size, void* d_ws, size_t ws_size,
                              hipStream_t stream) {
    const float* masks = (const float*)d_in[0];
    float* out = (float*)d_out;
    dim3 grid(HH / TYO, BATCH);    // 16 x 32 = 512 blocks, 2 per CU
    label_gen_roll<<<grid, NT, 0, stream>>>(masks, out);
}